// Round 4
// baseline (241.083 us; speedup 1.0000x reference)
//
#include <hip/hip_runtime.h>
#include <hip/hip_bf16.h>
#include <stdint.h>

#define NROWS 8192
#define DIMQ 1024
#define DIMU 1024
#define NCH 16

#define BM 128
#define BN 128
#define BK 64

typedef __attribute__((ext_vector_type(4))) float f32x4;
typedef __attribute__((ext_vector_type(8))) short bf16x8;

__device__ __forceinline__ short f2bf(float f) {
    union { __hip_bfloat16 h; short s; } u;
    u.h = __float2bfloat16(f);
    return u.s;
}

// ---------------- fused f32 -> bf16 convert for q and W_stack ----------------
__global__ void cvt2_kernel(const float* __restrict__ q, const float* __restrict__ Ws,
                            short* __restrict__ qb, short* __restrict__ Wb) {
    const int nq = NROWS * DIMQ / 8;
    const int nw = NCH * DIMU * DIMQ / 8;
    int i0 = blockIdx.x * blockDim.x + threadIdx.x;
    int stride = gridDim.x * blockDim.x;
    for (int i = i0; i < nq; i += stride) {
        const f32x4* p = reinterpret_cast<const f32x4*>(q + (size_t)i * 8);
        f32x4 a = p[0], b = p[1];
        bf16x8 o;
        o[0] = f2bf(a[0]); o[1] = f2bf(a[1]); o[2] = f2bf(a[2]); o[3] = f2bf(a[3]);
        o[4] = f2bf(b[0]); o[5] = f2bf(b[1]); o[6] = f2bf(b[2]); o[7] = f2bf(b[3]);
        *reinterpret_cast<bf16x8*>(qb + (size_t)i * 8) = o;
    }
    for (int i = i0; i < nw; i += stride) {
        const f32x4* p = reinterpret_cast<const f32x4*>(Ws + (size_t)i * 8);
        f32x4 a = p[0], b = p[1];
        bf16x8 o;
        o[0] = f2bf(a[0]); o[1] = f2bf(a[1]); o[2] = f2bf(a[2]); o[3] = f2bf(a[3]);
        o[4] = f2bf(b[0]); o[5] = f2bf(b[1]); o[6] = f2bf(b[2]); o[7] = f2bf(b[3]);
        *reinterpret_cast<bf16x8*>(Wb + (size_t)i * 8) = o;
    }
}

// ---------------- gate: top-2 + normalize, LDS histogram ----------------
__global__ void gate_kernel(const float* __restrict__ weights,
                            int* __restrict__ cnt,
                            int* __restrict__ rowlist,
                            float* __restrict__ wgt) {
    __shared__ int lcnt[NCH];
    __shared__ int lbase[NCH];
    const int t = threadIdx.x;
    const int b = blockIdx.x * blockDim.x + t;
    if (t < NCH) lcnt[t] = 0;
    __syncthreads();

    float w[NCH];
    const f32x4* wp = reinterpret_cast<const f32x4*>(weights + (size_t)b * NCH);
#pragma unroll
    for (int i = 0; i < 4; ++i) {
        f32x4 v = wp[i];
        w[i * 4 + 0] = v[0]; w[i * 4 + 1] = v[1];
        w[i * 4 + 2] = v[2]; w[i * 4 + 3] = v[3];
    }
    int i0 = 0; float v0 = w[0];
#pragma unroll
    for (int i = 1; i < NCH; ++i) if (w[i] > v0) { v0 = w[i]; i0 = i; }
    int i1 = (i0 == 0) ? 1 : 0; float v1 = w[i1];
#pragma unroll
    for (int i = 0; i < NCH; ++i) if (i != i0 && w[i] > v1) { v1 = w[i]; i1 = i; }
    float s = v0 + v1;
    s = (s < 1e-8f) ? 1e-8f : s;
    float n0 = v0 / s, n1 = v1 / s;

    int p0 = atomicAdd(&lcnt[i0], 1);
    int p1 = atomicAdd(&lcnt[i1], 1);
    __syncthreads();
    if (t < NCH) lbase[t] = atomicAdd(&cnt[t], lcnt[t]);
    __syncthreads();

    int o0 = lbase[i0] + p0;
    int o1 = lbase[i1] + p1;
    rowlist[(size_t)i0 * NROWS + o0] = b;  wgt[(size_t)i0 * NROWS + o0] = n0;
    rowlist[(size_t)i1 * NROWS + o1] = b;  wgt[(size_t)i1 * NROWS + o1] = n1;
}

// ================= bf16 grouped gather-GEMM (m97 structure) =================
// global_load_lds width-16 staging (A gathered via per-lane global src, linear
// LDS dest), single-buffered 2-barrier K-loop, 1-D grid with chart->XCD pinning.
__global__ __launch_bounds__(256, 3) void moe_gemm_bf(
    const short* __restrict__ qb, const short* __restrict__ Wb,
    const int* __restrict__ cnt, const int* __restrict__ rowlist,
    const float* __restrict__ wgt, float* __restrict__ out)
{
    // id%8 == chart%8  ->  all blocks of a chart on one XCD (W_c L2-resident)
    const int id  = blockIdx.x;
    const int xcd = id & 7;
    const int k   = id >> 3;          // 0..1023
    const int c   = xcd + ((k >> 9) << 3);
    const int kk  = k & 511;
    const int n0  = (kk & 7) * BN;    // n varies fastest: A-tile reused across 8 blocks
    const int m0  = (kk >> 3) * BM;

    const int count = cnt[c];
    if (m0 >= count) return;

    __shared__ short sA[BM * BK];     // 16 KB, linear (gload_lds requires it)
    __shared__ short sB[BN * BK];     // 16 KB
    __shared__ int   sRow[BM];
    __shared__ float sW[BM];

    const int t = threadIdx.x;
    if (t < BM) {
        int gi = m0 + t;
        int r = 0; float wv_ = 0.f;
        if (gi < count) {
            r   = rowlist[(size_t)c * NROWS + gi];
            wv_ = wgt[(size_t)c * NROWS + gi];
        }
        sRow[t] = r; sW[t] = wv_;
    }
    __syncthreads();

    // staging: tile = 128 rows x 64 bf16 = 1024 x 16B chunks; chunk = i*256 + t
    // LDS dest = chunk*16 bytes -> within a wave: uniform base + lane*16  (m104/m108)
    const short* aSrc[4];
    const short* bSrc[4];
#pragma unroll
    for (int i = 0; i < 4; ++i) {
        int ch = i * 256 + t;
        int r  = ch >> 3;
        int c8 = ch & 7;
        aSrc[i] = qb + (size_t)sRow[r] * DIMQ + c8 * 8;
        bSrc[i] = Wb + (size_t)c * ((size_t)DIMU * DIMQ) + (size_t)(n0 + r) * DIMQ + c8 * 8;
    }

    const int lane = t & 63;
    const int wv   = t >> 6;
    const int wm   = (wv >> 1) * 64;
    const int wn   = (wv & 1) * 64;
    const int rr   = lane & 15;
    const int g    = lane >> 4;

    f32x4 acc[4][4];
#pragma unroll
    for (int r = 0; r < 4; ++r)
#pragma unroll
        for (int cc = 0; cc < 4; ++cc)
            acc[r][cc] = (f32x4){0.f, 0.f, 0.f, 0.f};

    const int NKT = DIMQ / BK;  // 16
    for (int kt = 0; kt < NKT; ++kt) {
        __syncthreads();   // previous iter's ds_reads done before LDS overwrite
#pragma unroll
        for (int i = 0; i < 4; ++i)
            __builtin_amdgcn_global_load_lds(aSrc[i] + kt * BK, &sA[(i * 256 + t) * 8], 16, 0, 0);
#pragma unroll
        for (int i = 0; i < 4; ++i)
            __builtin_amdgcn_global_load_lds(bSrc[i] + kt * BK, &sB[(i * 256 + t) * 8], 16, 0, 0);
        __syncthreads();   // compiler drains vmcnt(0) before s_barrier (m97 behavior)

#pragma unroll
        for (int ks = 0; ks < 2; ++ks) {
            bf16x8 af[4], bfr[4];
#pragma unroll
            for (int r = 0; r < 4; ++r) {
                af[r]  = *reinterpret_cast<const bf16x8*>(&sA[(wm + r * 16 + rr) * BK + ks * 32 + g * 8]);
                bfr[r] = *reinterpret_cast<const bf16x8*>(&sB[(wn + r * 16 + rr) * BK + ks * 32 + g * 8]);
            }
#pragma unroll
            for (int r = 0; r < 4; ++r)
#pragma unroll
                for (int cc = 0; cc < 4; ++cc)
                    acc[r][cc] = __builtin_amdgcn_mfma_f32_16x16x32_bf16(af[r], bfr[cc], acc[r][cc], 0, 0, 0);
        }
    }

    // epilogue: gate-scale + scatter-add (each out element hit by exactly 2 charts)
#pragma unroll
    for (int r = 0; r < 4; ++r) {
#pragma unroll
        for (int cc = 0; cc < 4; ++cc) {
#pragma unroll
            for (int j = 0; j < 4; ++j) {
                int rowInTile = wm + r * 16 + g * 4 + j;   // C/D: row=(lane>>4)*4+reg, col=lane&15 (m89)
                int gi = m0 + rowInTile;
                if (gi < count) {
                    int   orow = sRow[rowInTile];
                    float wgx  = sW[rowInTile];
                    int   col  = n0 + wn + cc * 16 + rr;
                    atomicAdd(&out[(size_t)orow * DIMU + col], acc[r][cc][j] * wgx);
                }
            }
        }
    }
}

// ================= fallback f32-staging GEMM (proven round-2 path) =================
#define BKF 32
#define LDSTRF 40
typedef __attribute__((ext_vector_type(4))) short s16x4;

__global__ __launch_bounds__(256, 2) void moe_gemm_f32(
    const float* __restrict__ q, const float* __restrict__ Wst,
    const int* __restrict__ cnt, const int* __restrict__ rowlist,
    const float* __restrict__ wgt, float* __restrict__ out)
{
    const int c  = blockIdx.z;
    const int n0 = blockIdx.x * BN;
    const int m0 = blockIdx.y * BM;
    const int count = cnt[c];
    if (m0 >= count) return;

    __shared__ short sA[BM * LDSTRF];
    __shared__ short sB[BN * LDSTRF];
    __shared__ int   sRow[BM];
    __shared__ float sW[BM];

    const int t = threadIdx.x;
    if (t < BM) {
        int gi = m0 + t;
        int r = 0; float w = 0.f;
        if (gi < count) {
            r = rowlist[(size_t)c * NROWS + gi];
            w = wgt[(size_t)c * NROWS + gi];
        }
        sRow[t] = r; sW[t] = w;
    }
    __syncthreads();

    const float* aBase[4];
    const float* bBase[4];
    int ldsOff[4];
#pragma unroll
    for (int i = 0; i < 4; ++i) {
        int f  = t + i * 256;
        int r  = f >> 3;
        int c4 = f & 7;
        aBase[i]  = q   + (size_t)sRow[r] * DIMQ + c4 * 4;
        bBase[i]  = Wst + (size_t)c * ((size_t)DIMU * DIMQ) + (size_t)(n0 + r) * DIMQ + c4 * 4;
        ldsOff[i] = r * LDSTRF + c4 * 4;
    }

    const int lane = t & 63;
    const int wv   = t >> 6;
    const int wm   = (wv >> 1) * 64;
    const int wn   = (wv & 1) * 64;
    const int rr   = lane & 15;
    const int g    = lane >> 4;

    f32x4 acc[4][4];
#pragma unroll
    for (int r = 0; r < 4; ++r)
#pragma unroll
        for (int cc = 0; cc < 4; ++cc)
            acc[r][cc] = (f32x4){0.f, 0.f, 0.f, 0.f};

    f32x4 pa[4], pb[4];
#pragma unroll
    for (int i = 0; i < 4; ++i) {
        pa[i] = *reinterpret_cast<const f32x4*>(aBase[i]);
        pb[i] = *reinterpret_cast<const f32x4*>(bBase[i]);
    }

    const int NKT = DIMQ / BKF;
    for (int kt = 0; kt < NKT; ++kt) {
        __syncthreads();
#pragma unroll
        for (int i = 0; i < 4; ++i) {
            s16x4 va, vb;
#pragma unroll
            for (int j = 0; j < 4; ++j) { va[j] = f2bf(pa[i][j]); vb[j] = f2bf(pb[i][j]); }
            *reinterpret_cast<s16x4*>(&sA[ldsOff[i]]) = va;
            *reinterpret_cast<s16x4*>(&sB[ldsOff[i]]) = vb;
        }
        __syncthreads();

        if (kt + 1 < NKT) {
            int k = (kt + 1) * BKF;
#pragma unroll
            for (int i = 0; i < 4; ++i) {
                pa[i] = *reinterpret_cast<const f32x4*>(aBase[i] + k);
                pb[i] = *reinterpret_cast<const f32x4*>(bBase[i] + k);
            }
        }

        bf16x8 af[4], bfr[4];
#pragma unroll
        for (int r = 0; r < 4; ++r) {
            af[r]  = *reinterpret_cast<const bf16x8*>(&sA[(wm + r * 16 + rr) * LDSTRF + g * 8]);
            bfr[r] = *reinterpret_cast<const bf16x8*>(&sB[(wn + r * 16 + rr) * LDSTRF + g * 8]);
        }
#pragma unroll
        for (int r = 0; r < 4; ++r)
#pragma unroll
            for (int cc = 0; cc < 4; ++cc)
                acc[r][cc] = __builtin_amdgcn_mfma_f32_16x16x32_bf16(af[r], bfr[cc], acc[r][cc], 0, 0, 0);
    }

#pragma unroll
    for (int r = 0; r < 4; ++r) {
#pragma unroll
        for (int cc = 0; cc < 4; ++cc) {
#pragma unroll
            for (int j = 0; j < 4; ++j) {
                int rowInTile = wm + r * 16 + g * 4 + j;
                int gi = m0 + rowInTile;
                if (gi < count) {
                    int   orow = sRow[rowInTile];
                    float w    = sW[rowInTile];
                    int   col  = n0 + wn + cc * 16 + rr;
                    atomicAdd(&out[(size_t)orow * DIMU + col], acc[r][cc][j] * w);
                }
            }
        }
    }
}

extern "C" void kernel_launch(void* const* d_in, const int* in_sizes, int n_in,
                              void* d_out, int out_size, void* d_ws, size_t ws_size,
                              hipStream_t stream) {
    const float* q  = (const float*)d_in[0];
    const float* w  = (const float*)d_in[1];
    const float* Ws = (const float*)d_in[2];
    float* out = (float*)d_out;

    const size_t qbf_bytes  = (size_t)NROWS * DIMQ * 2;              // 16.78 MB
    const size_t wbf_bytes  = (size_t)NCH * DIMU * (size_t)DIMQ * 2; // 33.55 MB
    const size_t meta_bytes = 256 + (size_t)NCH * NROWS * (sizeof(int) + sizeof(float));
    char* ws = (char*)d_ws;

    if (ws_size >= qbf_bytes + wbf_bytes + meta_bytes) {
        short* qb      = (short*)ws;
        short* Wb      = (short*)(ws + qbf_bytes);
        int*   cnt     = (int*)(ws + qbf_bytes + wbf_bytes);
        int*   rowlist = (int*)(ws + qbf_bytes + wbf_bytes + 256);
        float* wgt     = (float*)(ws + qbf_bytes + wbf_bytes + 256 + (size_t)NCH * NROWS * sizeof(int));

        hipMemsetAsync(cnt, 0, 256, stream);
        hipMemsetAsync(d_out, 0, (size_t)out_size * sizeof(float), stream);

        cvt2_kernel<<<2048, 256, 0, stream>>>(q, Ws, qb, Wb);
        gate_kernel<<<NROWS / 256, 256, 0, stream>>>(w, cnt, rowlist, wgt);

        // 1-D grid: 8 xcd-slots x 2 charts x 64 m-tiles x 8 n-tiles = 8192 blocks
        moe_gemm_bf<<<8192, 256, 0, stream>>>(qb, Wb, cnt, rowlist, wgt, out);
    } else {
        int*   cnt     = (int*)ws;
        int*   rowlist = (int*)(ws + 256);
        float* wgt     = (float*)(ws + 256 + (size_t)NCH * NROWS * sizeof(int));

        hipMemsetAsync(cnt, 0, 256, stream);
        hipMemsetAsync(d_out, 0, (size_t)out_size * sizeof(float), stream);

        gate_kernel<<<NROWS / 256, 256, 0, stream>>>(w, cnt, rowlist, wgt);

        dim3 grid(DIMU / BN, NROWS / BM, NCH);
        moe_gemm_f32<<<grid, 256, 0, stream>>>(q, Ws, cnt, rowlist, wgt, out);
    }
}

// Round 5
// 227.822 us; speedup vs baseline: 1.0582x; 1.0582x over previous
//
#include <hip/hip_runtime.h>
#include <hip/hip_bf16.h>
#include <stdint.h>

#define NROWS 8192
#define DIMQ 1024
#define DIMU 1024
#define NCH 16

#define BM 128
#define BN 128
#define BK 64
#define LDSTR 72   // bf16 elems per LDS row: 144B stride spreads b128 ops over all bank groups
#define MSLOTS 16  // m-tile slots per chart; grid-stride loop handles count>MSLOTS*BM

typedef __attribute__((ext_vector_type(4))) float f32x4;
typedef __attribute__((ext_vector_type(4))) short s16x4;
typedef __attribute__((ext_vector_type(8))) short bf16x8;

__device__ __forceinline__ short f2bf(float f) {
    union { __hip_bfloat16 h; short s; } u;
    u.h = __float2bfloat16(f);
    return u.s;
}

// ---------------- fused f32 -> bf16 convert for q and W_stack ----------------
__global__ void cvt2_kernel(const float* __restrict__ q, const float* __restrict__ Ws,
                            short* __restrict__ qb, short* __restrict__ Wb) {
    const int nq = NROWS * DIMQ / 8;
    const int nw = NCH * DIMU * DIMQ / 8;
    int i0 = blockIdx.x * blockDim.x + threadIdx.x;
    int stride = gridDim.x * blockDim.x;
    for (int i = i0; i < nq; i += stride) {
        const f32x4* p = reinterpret_cast<const f32x4*>(q + (size_t)i * 8);
        f32x4 a = p[0], b = p[1];
        bf16x8 o;
        o[0] = f2bf(a[0]); o[1] = f2bf(a[1]); o[2] = f2bf(a[2]); o[3] = f2bf(a[3]);
        o[4] = f2bf(b[0]); o[5] = f2bf(b[1]); o[6] = f2bf(b[2]); o[7] = f2bf(b[3]);
        *reinterpret_cast<bf16x8*>(qb + (size_t)i * 8) = o;
    }
    for (int i = i0; i < nw; i += stride) {
        const f32x4* p = reinterpret_cast<const f32x4*>(Ws + (size_t)i * 8);
        f32x4 a = p[0], b = p[1];
        bf16x8 o;
        o[0] = f2bf(a[0]); o[1] = f2bf(a[1]); o[2] = f2bf(a[2]); o[3] = f2bf(a[3]);
        o[4] = f2bf(b[0]); o[5] = f2bf(b[1]); o[6] = f2bf(b[2]); o[7] = f2bf(b[3]);
        *reinterpret_cast<bf16x8*>(Wb + (size_t)i * 8) = o;
    }
}

// ---------------- gate: top-2 + normalize, LDS histogram ----------------
__global__ void gate_kernel(const float* __restrict__ weights,
                            int* __restrict__ cnt,
                            int* __restrict__ rowlist,
                            float* __restrict__ wgt) {
    __shared__ int lcnt[NCH];
    __shared__ int lbase[NCH];
    const int t = threadIdx.x;
    const int b = blockIdx.x * blockDim.x + t;
    if (t < NCH) lcnt[t] = 0;
    __syncthreads();

    float w[NCH];
    const f32x4* wp = reinterpret_cast<const f32x4*>(weights + (size_t)b * NCH);
#pragma unroll
    for (int i = 0; i < 4; ++i) {
        f32x4 v = wp[i];
        w[i * 4 + 0] = v[0]; w[i * 4 + 1] = v[1];
        w[i * 4 + 2] = v[2]; w[i * 4 + 3] = v[3];
    }
    int i0 = 0; float v0 = w[0];
#pragma unroll
    for (int i = 1; i < NCH; ++i) if (w[i] > v0) { v0 = w[i]; i0 = i; }
    int i1 = (i0 == 0) ? 1 : 0; float v1 = w[i1];
#pragma unroll
    for (int i = 0; i < NCH; ++i) if (i != i0 && w[i] > v1) { v1 = w[i]; i1 = i; }
    float s = v0 + v1;
    s = (s < 1e-8f) ? 1e-8f : s;
    float n0 = v0 / s, n1 = v1 / s;

    int p0 = atomicAdd(&lcnt[i0], 1);
    int p1 = atomicAdd(&lcnt[i1], 1);
    __syncthreads();
    if (t < NCH) lbase[t] = atomicAdd(&cnt[t], lcnt[t]);
    __syncthreads();

    int o0 = lbase[i0] + p0;
    int o1 = lbase[i1] + p1;
    rowlist[(size_t)i0 * NROWS + o0] = b;  wgt[(size_t)i0 * NROWS + o0] = n0;
    rowlist[(size_t)i1 * NROWS + o1] = b;  wgt[(size_t)i1 * NROWS + o1] = n1;
}

// ================= bf16 grouped gather-GEMM =================
// Round-3 K-loop (reg-staged, padded LDS, load-latency hidden under MFMA)
// + round-4 chart->XCD pinning (W_c stays L2-resident, fetch ~35MB).
// Grid 2048: id = xcd(3b) | cbit(1b) | n(3b) | mslot(4b); grid-stride over m.
__global__ __launch_bounds__(256, 3) void moe_gemm_bf(
    const short* __restrict__ qb, const short* __restrict__ Wb,
    const int* __restrict__ cnt, const int* __restrict__ rowlist,
    const float* __restrict__ wgt, float* __restrict__ out)
{
    const int id    = blockIdx.x;
    const int xcd   = id & 7;
    const int rest  = id >> 3;               // 0..255
    const int c     = xcd + 8 * (rest & 1);  // chart pinned to xcd = c%8
    const int n0    = ((rest >> 1) & 7) * BN;
    const int mslot = rest >> 4;             // 0..15

    const int count = cnt[c];

    __shared__ short sA[BM * LDSTR];
    __shared__ short sB[BN * LDSTR];
    __shared__ int   sRow[BM];
    __shared__ float sW[BM];

    const int t    = threadIdx.x;
    const int lane = t & 63;
    const int wv   = t >> 6;
    const int wm   = (wv >> 1) * 64;
    const int wn   = (wv & 1) * 64;
    const int rr   = lane & 15;
    const int g    = lane >> 4;

    for (int m0 = mslot * BM; m0 < count; m0 += MSLOTS * BM) {
        __syncthreads();   // protect sRow/sW from previous iteration's epilogue reads
        if (t < BM) {
            int gi = m0 + t;
            int r = 0; float wv_ = 0.f;
            if (gi < count) {
                r   = rowlist[(size_t)c * NROWS + gi];
                wv_ = wgt[(size_t)c * NROWS + gi];
            }
            sRow[t] = r; sW[t] = wv_;
        }
        __syncthreads();

        // staging: tile = 128 rows x 64 bf16 = 1024 x 16B chunks; 4 chunks/thread/matrix
        const short* aSrc[4];
        const short* bSrc[4];
        int ldsO[4];
#pragma unroll
        for (int i = 0; i < 4; ++i) {
            int ch = i * 256 + t;
            int r  = ch >> 3;
            int c8 = ch & 7;
            aSrc[i] = qb + (size_t)sRow[r] * DIMQ + c8 * 8;
            bSrc[i] = Wb + (size_t)c * ((size_t)DIMU * DIMQ) + (size_t)(n0 + r) * DIMQ + c8 * 8;
            ldsO[i] = r * LDSTR + c8 * 8;
        }

        f32x4 acc[4][4];
#pragma unroll
        for (int r = 0; r < 4; ++r)
#pragma unroll
            for (int cc = 0; cc < 4; ++cc)
                acc[r][cc] = (f32x4){0.f, 0.f, 0.f, 0.f};

        bf16x8 pa[4], pb[4];
#pragma unroll
        for (int i = 0; i < 4; ++i) {
            pa[i] = *reinterpret_cast<const bf16x8*>(aSrc[i]);
            pb[i] = *reinterpret_cast<const bf16x8*>(bSrc[i]);
        }

        const int NKT = DIMQ / BK;  // 16
        for (int kt = 0; kt < NKT; ++kt) {
            __syncthreads();
#pragma unroll
            for (int i = 0; i < 4; ++i) {
                *reinterpret_cast<bf16x8*>(&sA[ldsO[i]]) = pa[i];
                *reinterpret_cast<bf16x8*>(&sB[ldsO[i]]) = pb[i];
            }
            __syncthreads();

            if (kt + 1 < NKT) {   // issue next tile's global loads; latency hides under MFMA below
                int k = (kt + 1) * BK;
#pragma unroll
                for (int i = 0; i < 4; ++i) {
                    pa[i] = *reinterpret_cast<const bf16x8*>(aSrc[i] + k);
                    pb[i] = *reinterpret_cast<const bf16x8*>(bSrc[i] + k);
                }
            }

#pragma unroll
            for (int ks = 0; ks < 2; ++ks) {
                bf16x8 af[4], bfr[4];
#pragma unroll
                for (int r = 0; r < 4; ++r) {
                    af[r]  = *reinterpret_cast<const bf16x8*>(&sA[(wm + r * 16 + rr) * LDSTR + ks * 32 + g * 8]);
                    bfr[r] = *reinterpret_cast<const bf16x8*>(&sB[(wn + r * 16 + rr) * LDSTR + ks * 32 + g * 8]);
                }
#pragma unroll
                for (int r = 0; r < 4; ++r)
#pragma unroll
                    for (int cc = 0; cc < 4; ++cc)
                        acc[r][cc] = __builtin_amdgcn_mfma_f32_16x16x32_bf16(af[r], bfr[cc], acc[r][cc], 0, 0, 0);
            }
        }

        // epilogue: gate-scale + scatter-add (each out element hit by exactly 2 charts)
#pragma unroll
        for (int r = 0; r < 4; ++r) {
#pragma unroll
            for (int cc = 0; cc < 4; ++cc) {
#pragma unroll
                for (int j = 0; j < 4; ++j) {
                    int rowInTile = wm + r * 16 + g * 4 + j;   // C/D: row=(lane>>4)*4+reg, col=lane&15 (m89)
                    int gi = m0 + rowInTile;
                    if (gi < count) {
                        int   orow = sRow[rowInTile];
                        float wgx  = sW[rowInTile];
                        int   col  = n0 + wn + cc * 16 + rr;
                        atomicAdd(&out[(size_t)orow * DIMU + col], acc[r][cc][j] * wgx);
                    }
                }
            }
        }
    }
}

// ================= fallback f32-staging GEMM (proven round-2 path) =================
#define BKF 32
#define LDSTRF 40

__global__ __launch_bounds__(256, 2) void moe_gemm_f32(
    const float* __restrict__ q, const float* __restrict__ Wst,
    const int* __restrict__ cnt, const int* __restrict__ rowlist,
    const float* __restrict__ wgt, float* __restrict__ out)
{
    const int c  = blockIdx.z;
    const int n0 = blockIdx.x * BN;
    const int m0 = blockIdx.y * BM;
    const int count = cnt[c];
    if (m0 >= count) return;

    __shared__ short sA[BM * LDSTRF];
    __shared__ short sB[BN * LDSTRF];
    __shared__ int   sRow[BM];
    __shared__ float sW[BM];

    const int t = threadIdx.x;
    if (t < BM) {
        int gi = m0 + t;
        int r = 0; float w = 0.f;
        if (gi < count) {
            r = rowlist[(size_t)c * NROWS + gi];
            w = wgt[(size_t)c * NROWS + gi];
        }
        sRow[t] = r; sW[t] = w;
    }
    __syncthreads();

    const float* aBase[4];
    const float* bBase[4];
    int ldsOff[4];
#pragma unroll
    for (int i = 0; i < 4; ++i) {
        int f  = t + i * 256;
        int r  = f >> 3;
        int c4 = f & 7;
        aBase[i]  = q   + (size_t)sRow[r] * DIMQ + c4 * 4;
        bBase[i]  = Wst + (size_t)c * ((size_t)DIMU * DIMQ) + (size_t)(n0 + r) * DIMQ + c4 * 4;
        ldsOff[i] = r * LDSTRF + c4 * 4;
    }

    const int lane = t & 63;
    const int wv   = t >> 6;
    const int wm   = (wv >> 1) * 64;
    const int wn   = (wv & 1) * 64;
    const int rr   = lane & 15;
    const int g    = lane >> 4;

    f32x4 acc[4][4];
#pragma unroll
    for (int r = 0; r < 4; ++r)
#pragma unroll
        for (int cc = 0; cc < 4; ++cc)
            acc[r][cc] = (f32x4){0.f, 0.f, 0.f, 0.f};

    f32x4 pa[4], pb[4];
#pragma unroll
    for (int i = 0; i < 4; ++i) {
        pa[i] = *reinterpret_cast<const f32x4*>(aBase[i]);
        pb[i] = *reinterpret_cast<const f32x4*>(bBase[i]);
    }

    const int NKT = DIMQ / BKF;
    for (int kt = 0; kt < NKT; ++kt) {
        __syncthreads();
#pragma unroll
        for (int i = 0; i < 4; ++i) {
            s16x4 va, vb;
#pragma unroll
            for (int j = 0; j < 4; ++j) { va[j] = f2bf(pa[i][j]); vb[j] = f2bf(pb[i][j]); }
            *reinterpret_cast<s16x4*>(&sA[ldsOff[i]]) = va;
            *reinterpret_cast<s16x4*>(&sB[ldsOff[i]]) = vb;
        }
        __syncthreads();

        if (kt + 1 < NKT) {
            int k = (kt + 1) * BKF;
#pragma unroll
            for (int i = 0; i < 4; ++i) {
                pa[i] = *reinterpret_cast<const f32x4*>(aBase[i] + k);
                pb[i] = *reinterpret_cast<const f32x4*>(bBase[i] + k);
            }
        }

        bf16x8 af[4], bfr[4];
#pragma unroll
        for (int r = 0; r < 4; ++r) {
            af[r]  = *reinterpret_cast<const bf16x8*>(&sA[(wm + r * 16 + rr) * LDSTRF + g * 8]);
            bfr[r] = *reinterpret_cast<const bf16x8*>(&sB[(wn + r * 16 + rr) * LDSTRF + g * 8]);
        }
#pragma unroll
        for (int r = 0; r < 4; ++r)
#pragma unroll
            for (int cc = 0; cc < 4; ++cc)
                acc[r][cc] = __builtin_amdgcn_mfma_f32_16x16x32_bf16(af[r], bfr[cc], acc[r][cc], 0, 0, 0);
    }

#pragma unroll
    for (int r = 0; r < 4; ++r) {
#pragma unroll
        for (int cc = 0; cc < 4; ++cc) {
#pragma unroll
            for (int j = 0; j < 4; ++j) {
                int rowInTile = wm + r * 16 + g * 4 + j;
                int gi = m0 + rowInTile;
                if (gi < count) {
                    int   orow = sRow[rowInTile];
                    float w    = sW[rowInTile];
                    int   col  = n0 + wn + cc * 16 + rr;
                    atomicAdd(&out[(size_t)orow * DIMU + col], acc[r][cc][j] * w);
                }
            }
        }
    }
}

extern "C" void kernel_launch(void* const* d_in, const int* in_sizes, int n_in,
                              void* d_out, int out_size, void* d_ws, size_t ws_size,
                              hipStream_t stream) {
    const float* q  = (const float*)d_in[0];
    const float* w  = (const float*)d_in[1];
    const float* Ws = (const float*)d_in[2];
    float* out = (float*)d_out;

    const size_t qbf_bytes  = (size_t)NROWS * DIMQ * 2;              // 16.78 MB
    const size_t wbf_bytes  = (size_t)NCH * DIMU * (size_t)DIMQ * 2; // 33.55 MB
    const size_t meta_bytes = 256 + (size_t)NCH * NROWS * (sizeof(int) + sizeof(float));
    char* ws = (char*)d_ws;

    if (ws_size >= qbf_bytes + wbf_bytes + meta_bytes) {
        short* qb      = (short*)ws;
        short* Wb      = (short*)(ws + qbf_bytes);
        int*   cnt     = (int*)(ws + qbf_bytes + wbf_bytes);
        int*   rowlist = (int*)(ws + qbf_bytes + wbf_bytes + 256);
        float* wgt     = (float*)(ws + qbf_bytes + wbf_bytes + 256 + (size_t)NCH * NROWS * sizeof(int));

        hipMemsetAsync(cnt, 0, 256, stream);
        hipMemsetAsync(d_out, 0, (size_t)out_size * sizeof(float), stream);

        cvt2_kernel<<<2048, 256, 0, stream>>>(q, Ws, qb, Wb);
        gate_kernel<<<NROWS / 256, 256, 0, stream>>>(w, cnt, rowlist, wgt);

        // 2048 blocks: 8 xcd x 2 charts x 8 n-tiles x 16 m-slots (grid-stride over m)
        moe_gemm_bf<<<2048, 256, 0, stream>>>(qb, Wb, cnt, rowlist, wgt, out);
    } else {
        int*   cnt     = (int*)ws;
        int*   rowlist = (int*)(ws + 256);
        float* wgt     = (float*)(ws + 256 + (size_t)NCH * NROWS * sizeof(int));

        hipMemsetAsync(cnt, 0, 256, stream);
        hipMemsetAsync(d_out, 0, (size_t)out_size * sizeof(float), stream);

        gate_kernel<<<NROWS / 256, 256, 0, stream>>>(w, cnt, rowlist, wgt);

        dim3 grid(DIMU / BN, NROWS / BM, NCH);
        moe_gemm_f32<<<grid, 256, 0, stream>>>(q, Ws, cnt, rowlist, wgt, out);
    }
}